// Round 1
// baseline (191.695 us; speedup 1.0000x reference)
//
#include <hip/hip_runtime.h>
#include <hip/hip_bf16.h>
#include <float.h>

// FactoredQuantizer: B=8192, M=16, N=256, C=64
// inputs  [B, M, C] fp32;  codebook [M, N, C] fp32
// out = codes [B, M, C] fp32 ++ idx [B, M] (as fp32 values)
//
// Round 10: latency-bound fix. Each main block now processes 4 row-tiles with
// a 3-buffer, 2-deep async pipeline: X staged via global_load_lds (width=16,
// no VGPR round trip) into linear LDS with a both-sides XOR chunk swizzle
// (source-permuted global addresses + XOR on the ds_read side) so the
// A-fragment reads stay bank-conflict-free without padding. Staged loads for
// tile t+2 are issued at the top of tile t, so they are drained by tile t's
// epilogue barrier and never stall the hot loop's B-fragment vmcnt FIFO.
// Hot loop (pure global dwordx4 + MFMA, zero LDS, zero barriers) unchanged.

#define BQ 8192
#define MQ 16
#define NQ 256
#define CQ 64
#define TILES 4

typedef short  shortx8 __attribute__((ext_vector_type(8)));
typedef float  f32x4   __attribute__((ext_vector_type(4)));

__device__ __forceinline__ unsigned short f2bf(float f, float& rem) {
    __hip_bfloat16 h = __float2bfloat16(f);          // RTN
    rem = f - __bfloat162float(h);                   // exact (Sterbenz)
    return __builtin_bit_cast(unsigned short, h);
}

// ---------------------------------------------------------------------------
// Prep: c2[m][n] = sum_k c^2 (fp32, wave-reduced over 8 k-chunk lanes) and
// codebook bf16x3 splits in MFMA B-fragment order:
//   cb3f[frag][lane][u], frag = ((m*3+j)*2+h)*16 + nt, lane = quad*16 + col,
//   holding codebook[m][nt*16+col][h*32+quad*8+u] split j.
// Thread t = (e, kc): e = m*256+n, kc = k-chunk (8 per row).
// Grid 256x128 so all CUs participate.
// ---------------------------------------------------------------------------
__global__ __launch_bounds__(128) void fq_prep_kernel(
        const float* __restrict__ codebook,
        unsigned short* __restrict__ cb3f,
        float* __restrict__ c2) {
    const int t  = blockIdx.x * 128 + threadIdx.x;   // 32768 threads
    const int kc = t & 7;
    const int e  = t >> 3;          // m*256 + n
    const int m  = e >> 8, n = e & 255;
    const int nt = n >> 4, col = n & 15;
    const int h = kc >> 2, quad = kc & 3;

    const float* src = codebook + (size_t)e * CQ + kc * 8;
    const float4 va = *(const float4*)src;
    const float4 vb = *(const float4*)(src + 4);
    const float el[8] = {va.x, va.y, va.z, va.w, vb.x, vb.y, vb.z, vb.w};

    // c2: partial sums live on 8 consecutive lanes (kc = lane&7)
    float s = 0.0f;
    #pragma unroll
    for (int u = 0; u < 8; ++u) s = fmaf(el[u], el[u], s);
    s += __shfl_xor(s, 1, 64);
    s += __shfl_xor(s, 2, 64);
    s += __shfl_xor(s, 4, 64);
    if (kc == 0) c2[e] = s;

    // 3-way bf16 split, packed 2 per dword
    uint p0[4], p1[4], p2[4];
    #pragma unroll
    for (int u = 0; u < 4; ++u) {
        float r1, r2, d;
        const float a = el[2 * u], b = el[2 * u + 1];
        const unsigned short a0 = f2bf(a, r1);
        const unsigned short a1 = f2bf(r1, r2);
        const unsigned short a2 = f2bf(r2, d);
        const unsigned short b0 = f2bf(b, r1);
        const unsigned short b1 = f2bf(r1, r2);
        const unsigned short b2 = f2bf(r2, d);
        p0[u] = (uint)a0 | ((uint)b0 << 16);
        p1[u] = (uint)a1 | ((uint)b1 << 16);
        p2[u] = (uint)a2 | ((uint)b2 << 16);
    }
    const int lane_f = quad * 16 + col;
    #pragma unroll
    for (int j = 0; j < 3; ++j) {
        const uint* p = (j == 0) ? p0 : (j == 1) ? p1 : p2;
        const int frag = ((m * 3 + j) * 2 + h) * 16 + nt;
        uint4* dst = (uint4*)(cb3f + ((size_t)frag * 64 + lane_f) * 8);
        *dst = make_uint4(p[0], p[1], p[2], p[3]);
    }
}

// ---------------------------------------------------------------------------
// Async X staging: 64 rows x 64 floats = 16 KB per tile = 1024 x 16B chunks.
// LDS destination is LINEAR (global_load_lds writes base + lane*16); bank-
// conflict freedom for the A-fragment reads comes from permuting the GLOBAL
// source chunk within each row: stored chunk q holds original chunk q^(r&7).
// Reader applies the same XOR (involution). Per 16-thread row group the
// fetched chunks are a permutation of the full 256B row -> still coalesced.
// ---------------------------------------------------------------------------
__device__ __forceinline__ void fq_stage(const float* __restrict__ inputs,
        int row0, int m, float* lds_base, int w, int lane) {
    #pragma unroll
    for (int i = 0; i < 4; ++i) {
        const int blk = i * 4 + w;            // 1KB block 0..15, wave-uniform
        const int f   = (blk << 6) + lane;    // chunk id 0..1023
        const int r   = f >> 4;               // row 0..63
        const int c   = (f & 15) ^ (r & 7);   // source chunk (swizzled)
        const float* src = inputs + ((size_t)(row0 + r) * MQ + m) * CQ + (c << 2);
        __builtin_amdgcn_global_load_lds(
            (const __attribute__((address_space(1))) void*)src,
            (__attribute__((address_space(3))) void*)(lds_base + (blk << 8)),
            16, 0, 0);
    }
}

// ---------------------------------------------------------------------------
// Main: block = 4 waves, 4 row-tiles of 64 rows x 256 codes. Wave (rg=w&1,
// chh=w>>1) owns 32 rows x 128 codes per tile: acc = 2 rt x 8 nt f32x4.
// Per tile: barrier -> issue stage(t+2) -> convert A (swizzled LDS reads) ->
// hot loop (48 coalesced B dwordx4 + 192 MFMA, no LDS/barriers) -> argmin
// epilogue. Grid 32x16 = 512 blocks = exactly 2/CU, no tail.
// ---------------------------------------------------------------------------
__global__ __launch_bounds__(256, 3) void fq_main_kernel(
        const float* __restrict__ inputs,
        const float* __restrict__ codebook,
        const unsigned short* __restrict__ cb3f,
        const float* __restrict__ c2,
        float* __restrict__ out_codes,
        float* __restrict__ out_idx) {
    const int m    = blockIdx.y;
    const int w    = threadIdx.x >> 6;
    const int lane = threadIdx.x & 63;
    const int quad = lane >> 4;
    const int col  = lane & 15;
    const int rg   = w & 1;    // row half
    const int chh  = w >> 1;   // code half
    const int rowB = blockIdx.x * (TILES * 64);

    __shared__ float sx[3][64][64];  // 48 KB, linear rows (256B), swizzled chunks
    __shared__ float s_c2[NQ];
    __shared__ float s_wb[2][64];
    __shared__ int   s_wi[2][64];
    __shared__ int   s_win[64];

    s_c2[threadIdx.x] = c2[m * NQ + threadIdx.x];

    // 2-deep prologue: tiles 0 and 1 in flight before the first barrier
    fq_stage(inputs, rowB,      m, &sx[0][0][0], w, lane);
    fq_stage(inputs, rowB + 64, m, &sx[1][0][0], w, lane);

    #pragma unroll 1
    for (int t = 0; t < TILES; ++t) {
        const int row0 = rowB + (t << 6);
        const float* sxb = &sx[t % 3][0][0];
        __syncthreads();   // sx[t%3] ready (pre-barrier vmcnt drain); s_c2 ready

        if (t + 2 < TILES)
            fq_stage(inputs, row0 + 128, m, &sx[(t + 2) % 3][0][0], w, lane);

        // ---- A-fragments: 12 (i,rt,h), converted per-lane into registers ----
        shortx8 afr[3][2][2];
        #pragma unroll
        for (int rt = 0; rt < 2; ++rt)
            #pragma unroll
            for (int h = 0; h < 2; ++h) {
                const int rr = rg * 32 + rt * 16 + col;
                const int p0 = (h * 8 + quad * 2) ^ (rr & 7);  // swizzled chunk
                const float* rowp = sxb + rr * 64;
                const float4 va = *(const float4*)(rowp + (p0 << 2));
                const float4 vb = *(const float4*)(rowp + ((p0 ^ 1) << 2));
                const float el[8] = {va.x, va.y, va.z, va.w,
                                     vb.x, vb.y, vb.z, vb.w};
                shortx8 a0, a1, a2;
                #pragma unroll
                for (int u = 0; u < 8; ++u) {
                    float r1, r2, d;
                    a0[u] = (short)f2bf(el[u], r1);
                    a1[u] = (short)f2bf(r1, r2);
                    a2[u] = (short)f2bf(r2, d);
                }
                afr[0][rt][h] = a0; afr[1][rt][h] = a1; afr[2][rt][h] = a2;
            }

        f32x4 acc[2][8];
        #pragma unroll
        for (int rt = 0; rt < 2; ++rt)
            #pragma unroll
            for (int nt = 0; nt < 8; ++nt)
                acc[rt][nt] = (f32x4){0.f, 0.f, 0.f, 0.f};

        // ---- hot loop: pure global dwordx4 + MFMA ----
        #pragma unroll
        for (int h = 0; h < 2; ++h) {
            #pragma unroll
            for (int j = 0; j < 3; ++j) {
                const int frag0 = ((m * 3 + j) * 2 + h) * 16 + chh * 8;
                const unsigned short* bp =
                    cb3f + ((size_t)frag0 * 64 + lane) * 8;
                shortx8 bfr[8];
                #pragma unroll
                for (int nt = 0; nt < 8; ++nt)
                    bfr[nt] = *(const shortx8*)(bp + (size_t)nt * 64 * 8);
                #pragma unroll
                for (int i = 0; i <= 2 - j; ++i) {
                    #pragma unroll
                    for (int nt = 0; nt < 8; ++nt) {
                        acc[0][nt] = __builtin_amdgcn_mfma_f32_16x16x32_bf16(
                            afr[i][0][h], bfr[nt], acc[0][nt], 0, 0, 0);
                        acc[1][nt] = __builtin_amdgcn_mfma_f32_16x16x32_bf16(
                            afr[i][1][h], bfr[nt], acc[1][nt], 0, 0, 0);
                    }
                }
            }
        }

        // ---- epilogue: d = c2 - 2*xc; per-row argmin, lowest n on ties ----
        float c2r[8];
        #pragma unroll
        for (int nt = 0; nt < 8; ++nt)
            c2r[nt] = s_c2[chh * 128 + nt * 16 + col];

        #pragma unroll
        for (int rt = 0; rt < 2; ++rt) {
            #pragma unroll
            for (int reg = 0; reg < 4; ++reg) {
                float bd = FLT_MAX; int bi = 0;
                #pragma unroll
                for (int nt = 0; nt < 8; ++nt) {
                    const float d = fmaf(-2.0f, acc[rt][nt][reg], c2r[nt]);
                    if (d < bd) { bd = d; bi = chh * 128 + nt * 16 + col; }
                }
                #pragma unroll
                for (int mask = 1; mask <= 8; mask <<= 1) {  // over 16 col lanes
                    const float od = __shfl_xor(bd, mask, 64);
                    const int   oi = __shfl_xor(bi, mask, 64);
                    if (od < bd || (od == bd && oi < bi)) { bd = od; bi = oi; }
                }
                if (col == 0) {
                    const int r = rg * 32 + rt * 16 + quad * 4 + reg;
                    s_wb[chh][r] = bd;
                    s_wi[chh][r] = bi;
                }
            }
        }
        __syncthreads();

        // cross code-half combine (chh=0 holds lower n: ties keep it)
        if (w == 0) {
            float bd = s_wb[0][lane]; int bi = s_wi[0][lane];
            const float od = s_wb[1][lane]; const int oi = s_wi[1][lane];
            if (od < bd || (od == bd && oi < bi)) { bd = od; bi = oi; }
            s_win[lane] = bi;
            out_idx[(size_t)(row0 + lane) * MQ + m] = (float)bi;
        }
        __syncthreads();

        // gather codes: wave w writes rows w*16..+15, lane = element (256B st)
        const float* cbm = codebook + (size_t)m * NQ * CQ;
        #pragma unroll 4
        for (int jj = 0; jj < 16; ++jj) {
            const int r  = w * 16 + jj;
            const int bn = s_win[r];
            out_codes[((size_t)(row0 + r) * MQ + m) * CQ + lane] =
                cbm[(size_t)bn * CQ + lane];
        }
    }
}

extern "C" void kernel_launch(void* const* d_in, const int* in_sizes, int n_in,
                              void* d_out, int out_size, void* d_ws, size_t ws_size,
                              hipStream_t stream) {
    const float* inputs   = (const float*)d_in[0];   // [B, M, C]
    const float* codebook = (const float*)d_in[1];   // [M, N, C]
    float* out_codes = (float*)d_out;                        // [B, M, C]
    float* out_idx   = (float*)d_out + (size_t)BQ * MQ * CQ; // [B, M]
    float*          c2   = (float*)d_ws;                     // 16 KB
    unsigned short* cb3f = (unsigned short*)(c2 + MQ * NQ);  // 1.5 MB

    fq_prep_kernel<<<dim3(256), 128, 0, stream>>>(codebook, cb3f, c2);

    fq_main_kernel<<<dim3(BQ / 64 / TILES, MQ), 256, 0, stream>>>(
        inputs, codebook, cb3f, c2, out_codes, out_idx);
}

// Round 2
// 127.316 us; speedup vs baseline: 1.5057x; 1.5057x over previous
//
#include <hip/hip_runtime.h>
#include <hip/hip_bf16.h>
#include <float.h>

// FactoredQuantizer: B=8192, M=16, N=256, C=64
// inputs  [B, M, C] fp32;  codebook [M, N, C] fp32
// out = codes [B, M, C] fp32 ++ idx [B, M] (as fp32 values)
//
// Round 11: revert to the round-9 (51 us) structure; round-10's 4-tile
// async pipeline spilled to scratch (+313 MB of HBM traffic). This round
// keeps register pressure explicitly inside the 3-waves/SIMD budget
// (136 -> 152 of 170) and applies only three latency fixes:
//   (1) TILES=2 per block: tile 1's B-fragment batches hit a warm L2,
//       block setup amortizes 2x, chains/CU 8 -> 4.
//   (2) T14 split-stage for tile 1: global float4 loads issued right after
//       the tile-0 barrier (+16 VGPRs), ds_write after the hot loop --
//       HBM latency hides under convert + 192 MFMAs.
//   (3) First B-batch (h=0,j=0) hoisted above the A-conversion so one of
//       the six serially-exposed L3-latency batches hides under VALU work.
// Hot loop itself (pure global dwordx4 + MFMA, zero LDS, zero barriers)
// is unchanged from the 51 us version.

#define BQ 8192
#define MQ 16
#define NQ 256
#define CQ 64
#define TILES 2

typedef short  shortx8 __attribute__((ext_vector_type(8)));
typedef float  f32x4   __attribute__((ext_vector_type(4)));

__device__ __forceinline__ unsigned short f2bf(float f, float& rem) {
    __hip_bfloat16 h = __float2bfloat16(f);          // RTN
    rem = f - __bfloat162float(h);                   // exact (Sterbenz)
    return __builtin_bit_cast(unsigned short, h);
}

// ---------------------------------------------------------------------------
// Prep: c2[m][n] = sum_k c^2 (fp32, wave-reduced over 8 k-chunk lanes) and
// codebook bf16x3 splits in MFMA B-fragment order:
//   cb3f[frag][lane][u], frag = ((m*3+j)*2+h)*16 + nt, lane = quad*16 + col,
//   holding codebook[m][nt*16+col][h*32+quad*8+u] split j.
// Thread t = (e, kc): e = m*256+n, kc = k-chunk (8 per row).
// Grid 256x128 so all CUs participate.
// ---------------------------------------------------------------------------
__global__ __launch_bounds__(128) void fq_prep_kernel(
        const float* __restrict__ codebook,
        unsigned short* __restrict__ cb3f,
        float* __restrict__ c2) {
    const int t  = blockIdx.x * 128 + threadIdx.x;   // 32768 threads
    const int kc = t & 7;
    const int e  = t >> 3;          // m*256 + n
    const int m  = e >> 8, n = e & 255;
    const int nt = n >> 4, col = n & 15;
    const int h = kc >> 2, quad = kc & 3;

    const float* src = codebook + (size_t)e * CQ + kc * 8;
    const float4 va = *(const float4*)src;
    const float4 vb = *(const float4*)(src + 4);
    const float el[8] = {va.x, va.y, va.z, va.w, vb.x, vb.y, vb.z, vb.w};

    // c2: partial sums live on 8 consecutive lanes (kc = lane&7)
    float s = 0.0f;
    #pragma unroll
    for (int u = 0; u < 8; ++u) s = fmaf(el[u], el[u], s);
    s += __shfl_xor(s, 1, 64);
    s += __shfl_xor(s, 2, 64);
    s += __shfl_xor(s, 4, 64);
    if (kc == 0) c2[e] = s;

    // 3-way bf16 split, packed 2 per dword
    uint p0[4], p1[4], p2[4];
    #pragma unroll
    for (int u = 0; u < 4; ++u) {
        float r1, r2, d;
        const float a = el[2 * u], b = el[2 * u + 1];
        const unsigned short a0 = f2bf(a, r1);
        const unsigned short a1 = f2bf(r1, r2);
        const unsigned short a2 = f2bf(r2, d);
        const unsigned short b0 = f2bf(b, r1);
        const unsigned short b1 = f2bf(r1, r2);
        const unsigned short b2 = f2bf(r2, d);
        p0[u] = (uint)a0 | ((uint)b0 << 16);
        p1[u] = (uint)a1 | ((uint)b1 << 16);
        p2[u] = (uint)a2 | ((uint)b2 << 16);
    }
    const int lane_f = quad * 16 + col;
    #pragma unroll
    for (int j = 0; j < 3; ++j) {
        const uint* p = (j == 0) ? p0 : (j == 1) ? p1 : p2;
        const int frag = ((m * 3 + j) * 2 + h) * 16 + nt;
        uint4* dst = (uint4*)(cb3f + ((size_t)frag * 64 + lane_f) * 8);
        *dst = make_uint4(p[0], p[1], p[2], p[3]);
    }
}

// ---------------------------------------------------------------------------
// Main: block = 4 waves, TILES=2 row-tiles of 64 rows x 256 codes.
// Wave (rg=w&1, chh=w>>1) owns 32 rows x 128 codes per tile:
// acc = 2 rt x 8 nt of f32x4 = 64 regs. X staged fp32 in padded LDS
// (double-buffered); tile-1 stage is issued as plain float4 loads right
// after the tile-0 barrier and ds_written after the hot loop (T14 split).
// K-loop: 8 coalesced B-fragment dwordx4 loads per (h,j) then (3-j)*16
// MFMAs; first batch hoisted above the A-conversion.
// Grid 64x16 = 1024 blocks = 4/CU, no tail.
// ---------------------------------------------------------------------------
__global__ __launch_bounds__(256, 3) void fq_main_kernel(
        const float* __restrict__ inputs,
        const float* __restrict__ codebook,
        const unsigned short* __restrict__ cb3f,
        const float* __restrict__ c2,
        float* __restrict__ out_codes,
        float* __restrict__ out_idx) {
    const int m    = blockIdx.y;
    const int w    = threadIdx.x >> 6;
    const int lane = threadIdx.x & 63;
    const int quad = lane >> 4;
    const int col  = lane & 15;
    const int rg   = w & 1;    // row half
    const int chh  = w >> 1;   // code half
    const int rowB = blockIdx.x * (TILES * 64);

    __shared__ float sx[2][64][68];  // 2 x 17408 B (stride 68: float4-aligned)
    __shared__ float s_c2[NQ];
    __shared__ float s_wb[2][64];
    __shared__ int   s_wi[2][64];
    __shared__ int   s_win[64];

    s_c2[threadIdx.x] = c2[m * NQ + threadIdx.x];

    // ---- stage tile 0: 64 rows x 64 floats, coalesced float4 ----
    #pragma unroll
    for (int i = 0; i < 4; ++i) {
        const int f = threadIdx.x + 256 * i;    // 0..1023 float4s
        const int r = f >> 4;
        const int c = (f & 15) * 4;
        const float4 v = *(const float4*)(
            inputs + ((size_t)(rowB + r) * MQ + m) * CQ + c);
        *(float4*)&sx[0][r][c] = v;
    }
    __syncthreads();

    #pragma unroll
    for (int t = 0; t < TILES; ++t) {
        const int row0 = rowB + t * 64;
        const float (*sxf)[68] = sx[t & 1];

        // ---- T14: issue next tile's global loads early (held in regs) ----
        float4 pf[4];
        if (t + 1 < TILES) {
            #pragma unroll
            for (int i = 0; i < 4; ++i) {
                const int f = threadIdx.x + 256 * i;
                const int r = f >> 4;
                const int c = (f & 15) * 4;
                pf[i] = *(const float4*)(
                    inputs + ((size_t)(row0 + 64 + r) * MQ + m) * CQ + c);
            }
        }

        // ---- hoist first B batch (h=0, j=0) above the A-conversion ----
        shortx8 bfr[8];
        {
            const int frag0 = (m * 3 * 2) * 16 + chh * 8;
            const unsigned short* bp = cb3f + ((size_t)frag0 * 64 + lane) * 8;
            #pragma unroll
            for (int nt = 0; nt < 8; ++nt)
                bfr[nt] = *(const shortx8*)(bp + (size_t)nt * 64 * 8);
        }

        // ---- A-fragments: 12 (i,rt,h), converted per-lane into registers ----
        shortx8 afr[3][2][2];
        #pragma unroll
        for (int rt = 0; rt < 2; ++rt)
            #pragma unroll
            for (int h = 0; h < 2; ++h) {
                const float* xp = &sxf[rg * 32 + rt * 16 + col][h * 32 + quad * 8];
                const float4 va = *(const float4*)xp;
                const float4 vb = *(const float4*)(xp + 4);
                const float el[8] = {va.x, va.y, va.z, va.w,
                                     vb.x, vb.y, vb.z, vb.w};
                shortx8 a0, a1, a2;
                #pragma unroll
                for (int u = 0; u < 8; ++u) {
                    float r1, r2, d;
                    a0[u] = (short)f2bf(el[u], r1);
                    a1[u] = (short)f2bf(r1, r2);
                    a2[u] = (short)f2bf(r2, d);
                }
                afr[0][rt][h] = a0; afr[1][rt][h] = a1; afr[2][rt][h] = a2;
            }

        f32x4 acc[2][8];
        #pragma unroll
        for (int rt = 0; rt < 2; ++rt)
            #pragma unroll
            for (int nt = 0; nt < 8; ++nt)
                acc[rt][nt] = (f32x4){0.f, 0.f, 0.f, 0.f};

        // ---- hot loop: pure global dwordx4 + MFMA ----
        #pragma unroll
        for (int h = 0; h < 2; ++h) {
            #pragma unroll
            for (int j = 0; j < 3; ++j) {
                if (!(h == 0 && j == 0)) {
                    const int frag0 = ((m * 3 + j) * 2 + h) * 16 + chh * 8;
                    const unsigned short* bp =
                        cb3f + ((size_t)frag0 * 64 + lane) * 8;
                    #pragma unroll
                    for (int nt = 0; nt < 8; ++nt)
                        bfr[nt] = *(const shortx8*)(bp + (size_t)nt * 64 * 8);
                }
                #pragma unroll
                for (int i = 0; i <= 2 - j; ++i) {
                    #pragma unroll
                    for (int nt = 0; nt < 8; ++nt) {
                        acc[0][nt] = __builtin_amdgcn_mfma_f32_16x16x32_bf16(
                            afr[i][0][h], bfr[nt], acc[0][nt], 0, 0, 0);
                        acc[1][nt] = __builtin_amdgcn_mfma_f32_16x16x32_bf16(
                            afr[i][1][h], bfr[nt], acc[1][nt], 0, 0, 0);
                    }
                }
            }
        }

        // ---- T14: write the prefetched next tile into the other buffer ----
        if (t + 1 < TILES) {
            #pragma unroll
            for (int i = 0; i < 4; ++i) {
                const int f = threadIdx.x + 256 * i;
                const int r = f >> 4;
                const int c = (f & 15) * 4;
                *(float4*)&sx[(t + 1) & 1][r][c] = pf[i];
            }
        }

        // ---- epilogue: d = c2 - 2*xc; per-row argmin, lowest n on ties ----
        float c2r[8];
        #pragma unroll
        for (int nt = 0; nt < 8; ++nt)
            c2r[nt] = s_c2[chh * 128 + nt * 16 + col];

        #pragma unroll
        for (int rt = 0; rt < 2; ++rt) {
            #pragma unroll
            for (int reg = 0; reg < 4; ++reg) {
                float bd = FLT_MAX; int bi = 0;
                #pragma unroll
                for (int nt = 0; nt < 8; ++nt) {
                    const float d = fmaf(-2.0f, acc[rt][nt][reg], c2r[nt]);
                    if (d < bd) { bd = d; bi = chh * 128 + nt * 16 + col; }
                }
                #pragma unroll
                for (int mask = 1; mask <= 8; mask <<= 1) {  // over 16 col lanes
                    const float od = __shfl_xor(bd, mask, 64);
                    const int   oi = __shfl_xor(bi, mask, 64);
                    if (od < bd || (od == bd && oi < bi)) { bd = od; bi = oi; }
                }
                if (col == 0) {
                    const int r = rg * 32 + rt * 16 + quad * 4 + reg;
                    s_wb[chh][r] = bd;
                    s_wi[chh][r] = bi;
                }
            }
        }
        __syncthreads();

        // cross code-half combine (chh=0 holds lower n: ties keep it)
        if (w == 0) {
            float bd = s_wb[0][lane]; int bi = s_wi[0][lane];
            const float od = s_wb[1][lane]; const int oi = s_wi[1][lane];
            if (od < bd || (od == bd && oi < bi)) { bd = od; bi = oi; }
            s_win[lane] = bi;
            out_idx[(size_t)(row0 + lane) * MQ + m] = (float)bi;
        }
        __syncthreads();

        // gather codes: wave w writes rows w*16..+15, lane = element (256B st)
        const float* cbm = codebook + (size_t)m * NQ * CQ;
        #pragma unroll 4
        for (int jj = 0; jj < 16; ++jj) {
            const int r  = w * 16 + jj;
            const int bn = s_win[r];
            out_codes[((size_t)(row0 + r) * MQ + m) * CQ + lane] =
                cbm[(size_t)bn * CQ + lane];
        }
    }
}

extern "C" void kernel_launch(void* const* d_in, const int* in_sizes, int n_in,
                              void* d_out, int out_size, void* d_ws, size_t ws_size,
                              hipStream_t stream) {
    const float* inputs   = (const float*)d_in[0];   // [B, M, C]
    const float* codebook = (const float*)d_in[1];   // [M, N, C]
    float* out_codes = (float*)d_out;                        // [B, M, C]
    float* out_idx   = (float*)d_out + (size_t)BQ * MQ * CQ; // [B, M]
    float*          c2   = (float*)d_ws;                     // 16 KB
    unsigned short* cb3f = (unsigned short*)(c2 + MQ * NQ);  // 1.5 MB

    fq_prep_kernel<<<dim3(256), 128, 0, stream>>>(codebook, cb3f, c2);

    fq_main_kernel<<<dim3(BQ / 64 / TILES, MQ), 256, 0, stream>>>(
        inputs, codebook, cb3f, c2, out_codes, out_idx);
}

// Round 3
// 121.122 us; speedup vs baseline: 1.5827x; 1.0511x over previous
//
#include <hip/hip_runtime.h>
#include <hip/hip_bf16.h>
#include <float.h>

// FactoredQuantizer: B=8192, M=16, N=256, C=64
// inputs  [B, M, C] fp32;  codebook [M, N, C] fp32
// out = codes [B, M, C] fp32 ++ idx [B, M] (as fp32 values)
//
// Round 12: back to the round-9 (51 us) structure exactly (rounds 10/11 both
// spilled: any extra live state across the 192-MFMA hot loop goes to scratch).
// The lever this round is WORK REDUCTION on the critical path: the bf16x3
// split switches from RTN (__float2bfloat16 + remainder, ~20 VALU ops/elem)
// to TRUNCATION (bits>>16; remainders exact by construction; after two
// truncations the third remainder fits bf16 exactly, so a0+a1+a2 == f
// bit-exactly). ~8.5 ops/elem including dword packing -> ~1500 fewer VALU
// instructions per wave between the stage barrier and the MFMAs.
// Also keeps the register-neutral (h=0,j=0) B-batch hoist above the
// conversion so one L2-latency exposure hides under the convert.

#define BQ 8192
#define MQ 16
#define NQ 256
#define CQ 64

typedef short  shortx8 __attribute__((ext_vector_type(8)));
typedef float  f32x4   __attribute__((ext_vector_type(4)));

#define HI_MASK 0xffff0000u

// Truncation 3-split of two floats a,b packed into three dwords
// (low short = a's bf16, high short = b's bf16). Exact: a0+a1+a2 == a.
__device__ __forceinline__ void split3_pair(float a, float b,
                                            uint& q0, uint& q1, uint& q2) {
    const uint ba = __builtin_bit_cast(uint, a);
    const uint bb = __builtin_bit_cast(uint, b);
    q0 = (ba >> 16) | (bb & HI_MASK);
    const float r1a = a - __builtin_bit_cast(float, ba & HI_MASK);
    const float r1b = b - __builtin_bit_cast(float, bb & HI_MASK);
    const uint c1a = __builtin_bit_cast(uint, r1a);
    const uint c1b = __builtin_bit_cast(uint, r1b);
    q1 = (c1a >> 16) | (c1b & HI_MASK);
    const float r2a = r1a - __builtin_bit_cast(float, c1a & HI_MASK);
    const float r2b = r1b - __builtin_bit_cast(float, c1b & HI_MASK);
    q2 = (__builtin_bit_cast(uint, r2a) >> 16) |
         (__builtin_bit_cast(uint, r2b) & HI_MASK);
}

// ---------------------------------------------------------------------------
// Prep: c2[m][n] = sum_k c^2 (fp32, wave-reduced over 8 k-chunk lanes) and
// codebook bf16x3 splits in MFMA B-fragment order:
//   cb3f[frag][lane][u], frag = ((m*3+j)*2+h)*16 + nt, lane = quad*16 + col,
//   holding codebook[m][nt*16+col][h*32+quad*8+u] split j.
// Thread t = (e, kc): e = m*256+n, kc = k-chunk (8 per row).
// Grid 256x128 so all CUs participate.
// ---------------------------------------------------------------------------
__global__ __launch_bounds__(128) void fq_prep_kernel(
        const float* __restrict__ codebook,
        unsigned short* __restrict__ cb3f,
        float* __restrict__ c2) {
    const int t  = blockIdx.x * 128 + threadIdx.x;   // 32768 threads
    const int kc = t & 7;
    const int e  = t >> 3;          // m*256 + n
    const int m  = e >> 8, n = e & 255;
    const int nt = n >> 4, col = n & 15;
    const int h = kc >> 2, quad = kc & 3;

    const float* src = codebook + (size_t)e * CQ + kc * 8;
    const float4 va = *(const float4*)src;
    const float4 vb = *(const float4*)(src + 4);
    const float el[8] = {va.x, va.y, va.z, va.w, vb.x, vb.y, vb.z, vb.w};

    // c2: partial sums live on 8 consecutive lanes (kc = lane&7)
    float s = 0.0f;
    #pragma unroll
    for (int u = 0; u < 8; ++u) s = fmaf(el[u], el[u], s);
    s += __shfl_xor(s, 1, 64);
    s += __shfl_xor(s, 2, 64);
    s += __shfl_xor(s, 4, 64);
    if (kc == 0) c2[e] = s;

    // 3-way truncation split, packed 2 per dword
    uint p0[4], p1[4], p2[4];
    #pragma unroll
    for (int u = 0; u < 4; ++u)
        split3_pair(el[2 * u], el[2 * u + 1], p0[u], p1[u], p2[u]);

    const int lane_f = quad * 16 + col;
    #pragma unroll
    for (int j = 0; j < 3; ++j) {
        const uint* p = (j == 0) ? p0 : (j == 1) ? p1 : p2;
        const int frag = ((m * 3 + j) * 2 + h) * 16 + nt;
        uint4* dst = (uint4*)(cb3f + ((size_t)frag * 64 + lane_f) * 8);
        *dst = make_uint4(p[0], p[1], p[2], p[3]);
    }
}

// ---------------------------------------------------------------------------
// Main: block = 4 waves over 64 rows x 256 codes; wave (rg=w&1, chh=w>>1)
// owns 32 rows x 128 codes: acc = 2 row-tiles x 8 n-tiles of f32x4 = 64 regs.
// X staged fp32 in LDS once; each lane converts its 12 A-fragments (i,rt,h)
// into registers via the truncation split. K-loop: 8 coalesced B-fragment
// dwordx4 loads per (h,j) then (3-j)*16 MFMAs; first batch hoisted above the
// conversion. No LDS / no barriers in the hot loop.
// ---------------------------------------------------------------------------
__global__ __launch_bounds__(256, 3) void fq_main_kernel(
        const float* __restrict__ inputs,
        const float* __restrict__ codebook,
        const unsigned short* __restrict__ cb3f,
        const float* __restrict__ c2,
        float* __restrict__ out_codes,
        float* __restrict__ out_idx) {
    const int m    = blockIdx.y;
    const int row0 = blockIdx.x * 64;
    const int w    = threadIdx.x >> 6;
    const int lane = threadIdx.x & 63;
    const int quad = lane >> 4;
    const int col  = lane & 15;
    const int rg   = w & 1;    // row half
    const int chh  = w >> 1;   // code half

    __shared__ float sxf[64][68];    // 17408 B (stride 68: float4-aligned)
    __shared__ float s_c2[NQ];
    __shared__ float s_wb[2][64];
    __shared__ int   s_wi[2][64];
    __shared__ int   s_win[64];

    s_c2[threadIdx.x] = c2[m * NQ + threadIdx.x];

    // ---- stage X fp32: 64 rows x 64 floats, coalesced float4 ----
    #pragma unroll
    for (int i = 0; i < 4; ++i) {
        const int f = threadIdx.x + 256 * i;    // 0..1023 float4s
        const int r = f >> 4;
        const int c = (f & 15) * 4;
        const float4 v = *(const float4*)(
            inputs + ((size_t)(row0 + r) * MQ + m) * CQ + c);
        *(float4*)&sxf[r][c] = v;
    }
    __syncthreads();

    // ---- hoist first B batch (h=0, j=0) above the A-conversion ----
    shortx8 bfr[8];
    {
        const int frag0 = (m * 3 * 2) * 16 + chh * 8;
        const unsigned short* bp = cb3f + ((size_t)frag0 * 64 + lane) * 8;
        #pragma unroll
        for (int nt = 0; nt < 8; ++nt)
            bfr[nt] = *(const shortx8*)(bp + (size_t)nt * 64 * 8);
    }

    // ---- A-fragments: 12 (i,rt,h), truncation-split into registers ----
    shortx8 afr[3][2][2];
    #pragma unroll
    for (int rt = 0; rt < 2; ++rt)
        #pragma unroll
        for (int h = 0; h < 2; ++h) {
            const float* xp = &sxf[rg * 32 + rt * 16 + col][h * 32 + quad * 8];
            const float4 va = *(const float4*)xp;
            const float4 vb = *(const float4*)(xp + 4);
            const float el[8] = {va.x, va.y, va.z, va.w, vb.x, vb.y, vb.z, vb.w};
            uint q0[4], q1[4], q2[4];
            #pragma unroll
            for (int u = 0; u < 4; ++u)
                split3_pair(el[2 * u], el[2 * u + 1], q0[u], q1[u], q2[u]);
            afr[0][rt][h] = __builtin_bit_cast(shortx8,
                make_uint4(q0[0], q0[1], q0[2], q0[3]));
            afr[1][rt][h] = __builtin_bit_cast(shortx8,
                make_uint4(q1[0], q1[1], q1[2], q1[3]));
            afr[2][rt][h] = __builtin_bit_cast(shortx8,
                make_uint4(q2[0], q2[1], q2[2], q2[3]));
        }

    f32x4 acc[2][8];
    #pragma unroll
    for (int rt = 0; rt < 2; ++rt)
        #pragma unroll
        for (int nt = 0; nt < 8; ++nt)
            acc[rt][nt] = (f32x4){0.f, 0.f, 0.f, 0.f};

    // ---- hot loop: pure global dwordx4 + MFMA ----
    #pragma unroll
    for (int h = 0; h < 2; ++h) {
        #pragma unroll
        for (int j = 0; j < 3; ++j) {
            if (!(h == 0 && j == 0)) {
                const int frag0 = ((m * 3 + j) * 2 + h) * 16 + chh * 8;
                const unsigned short* bp =
                    cb3f + ((size_t)frag0 * 64 + lane) * 8;
                #pragma unroll
                for (int nt = 0; nt < 8; ++nt)
                    bfr[nt] = *(const shortx8*)(bp + (size_t)nt * 64 * 8);
            }
            #pragma unroll
            for (int i = 0; i <= 2 - j; ++i) {
                #pragma unroll
                for (int nt = 0; nt < 8; ++nt) {
                    acc[0][nt] = __builtin_amdgcn_mfma_f32_16x16x32_bf16(
                        afr[i][0][h], bfr[nt], acc[0][nt], 0, 0, 0);
                    acc[1][nt] = __builtin_amdgcn_mfma_f32_16x16x32_bf16(
                        afr[i][1][h], bfr[nt], acc[1][nt], 0, 0, 0);
                }
            }
        }
    }

    // ---- epilogue: d = c2 - 2*xc; per-row argmin, lowest n on ties ----
    float c2r[8];
    #pragma unroll
    for (int nt = 0; nt < 8; ++nt)
        c2r[nt] = s_c2[chh * 128 + nt * 16 + col];

    #pragma unroll
    for (int rt = 0; rt < 2; ++rt) {
        #pragma unroll
        for (int reg = 0; reg < 4; ++reg) {
            float bd = FLT_MAX; int bi = 0;
            #pragma unroll
            for (int nt = 0; nt < 8; ++nt) {
                const float d = fmaf(-2.0f, acc[rt][nt][reg], c2r[nt]);
                if (d < bd) { bd = d; bi = chh * 128 + nt * 16 + col; }
            }
            #pragma unroll
            for (int mask = 1; mask <= 8; mask <<= 1) {   // over 16 col lanes
                const float od = __shfl_xor(bd, mask, 64);
                const int   oi = __shfl_xor(bi, mask, 64);
                if (od < bd || (od == bd && oi < bi)) { bd = od; bi = oi; }
            }
            if (col == 0) {
                const int r = rg * 32 + rt * 16 + quad * 4 + reg;
                s_wb[chh][r] = bd;
                s_wi[chh][r] = bi;
            }
        }
    }
    __syncthreads();

    // cross code-half combine (chh=0 holds lower n: ties keep it)
    if (w == 0) {
        float bd = s_wb[0][lane]; int bi = s_wi[0][lane];
        const float od = s_wb[1][lane]; const int oi = s_wi[1][lane];
        if (od < bd || (od == bd && oi < bi)) { bd = od; bi = oi; }
        s_win[lane] = bi;
        out_idx[(size_t)(row0 + lane) * MQ + m] = (float)bi;
    }
    __syncthreads();

    // gather codes: wave w writes rows w*16..+15, lane = element (256B st)
    const float* cbm = codebook + (size_t)m * NQ * CQ;
    #pragma unroll 4
    for (int jj = 0; jj < 16; ++jj) {
        const int r  = w * 16 + jj;
        const int bn = s_win[r];
        out_codes[((size_t)(row0 + r) * MQ + m) * CQ + lane] =
            cbm[(size_t)bn * CQ + lane];
    }
}

extern "C" void kernel_launch(void* const* d_in, const int* in_sizes, int n_in,
                              void* d_out, int out_size, void* d_ws, size_t ws_size,
                              hipStream_t stream) {
    const float* inputs   = (const float*)d_in[0];   // [B, M, C]
    const float* codebook = (const float*)d_in[1];   // [M, N, C]
    float* out_codes = (float*)d_out;                        // [B, M, C]
    float* out_idx   = (float*)d_out + (size_t)BQ * MQ * CQ; // [B, M]
    float*          c2   = (float*)d_ws;                     // 16 KB
    unsigned short* cb3f = (unsigned short*)(c2 + MQ * NQ);  // 1.5 MB

    fq_prep_kernel<<<dim3(256), 128, 0, stream>>>(codebook, cb3f, c2);

    fq_main_kernel<<<dim3(BQ / 64, MQ), 256, 0, stream>>>(
        inputs, codebook, cb3f, c2, out_codes, out_idx);
}